// Round 9
// baseline (273.233 us; speedup 1.0000x reference)
//
#include <hip/hip_runtime.h>
#include <hip/hip_bf16.h>
#include <math.h>

#define DEV __device__ __forceinline__

#define BB 2
#define VV 6
#define CC 128
#define NQ 1200
#define HH 8
#define PTSN 4
#define FFND 256
#define LVLSN 4
#define LTOT 29750
#define NROWS (BB*NQ)

__constant__ int c_W[4] = {200,100,50,25};
__constant__ int c_H[4] = {112,56,28,14};
__constant__ int c_S[4] = {0,22400,28000,29400};

DEV float bflo(unsigned u){ union{unsigned i; float f;}x; x.i = u<<16; return x.f; }
DEV float bfhi(unsigned u){ union{unsigned i; float f;}x; x.i = u&0xffff0000u; return x.f; }
DEV unsigned short f2bf(float f){ union{float f; unsigned i;}x; x.f=f; unsigned i=x.i;
  return (unsigned short)((i + 0x7fffu + ((i>>16)&1u))>>16); }
DEV unsigned addbf2(unsigned a, unsigned b){
  float lo = bflo(a)+bflo(b); float hi = bfhi(a)+bfhi(b);
  return (unsigned)f2bf(lo) | ((unsigned)f2bf(hi)<<16);
}
DEV float sigm(float z){ return 1.f/(1.f+__expf(-z)); }

typedef __attribute__((ext_vector_type(8))) short bf16x8;
typedef __attribute__((ext_vector_type(4))) float f32x4;

// ---------------- fused setup: bucket(2) + wt(16) + cw2t(16) + xpose(76) + qpe(600) ----------------
__global__ void k_misc(const int* __restrict__ view, int* __restrict__ order,
                       int* __restrict__ counts,
                       const float* __restrict__ vw, unsigned short* __restrict__ wt,
                       const float* __restrict__ cw2, unsigned short* __restrict__ cw2t,
                       const float* __restrict__ iqf, float* __restrict__ x,
                       const float* __restrict__ pos,
                       const float* __restrict__ w1, const float* __restrict__ b1,
                       const float* __restrict__ w2, const float* __restrict__ b2,
                       float* __restrict__ qpe){
  int bid = blockIdx.x;
  int t = threadIdx.x;
  if(bid < BB){
    if(t < 64){
      int b = bid; int lane = t;
      int base0=0,base1=0,base2=0,base3=0,base4=0,base5=0;
      for(int c0=0;c0<NQ;c0+=64){
        int n = c0 + lane;
        int v = (n<NQ) ? view[b*NQ+n] : -1;
        unsigned long long lower = (lane==63)? 0x7fffffffffffffffull : ((1ull<<lane)-1ull);
        #define BUCKET_STEP(VVV, BASE) { \
          unsigned long long mk = __ballot(v==VVV); \
          if(v==VVV){ int r = BASE + __popcll(mk & lower); order[(b*VV+VVV)*NQ + r] = n; } \
          BASE += __popcll(mk); }
        BUCKET_STEP(0, base0) BUCKET_STEP(1, base1) BUCKET_STEP(2, base2)
        BUCKET_STEP(3, base3) BUCKET_STEP(4, base4) BUCKET_STEP(5, base5)
        #undef BUCKET_STEP
      }
      if(lane==0){
        counts[b*VV+0]=base0; counts[b*VV+1]=base1; counts[b*VV+2]=base2;
        counts[b*VV+3]=base3; counts[b*VV+4]=base4; counts[b*VV+5]=base5;
      }
    }
  } else if(bid < BB+16){
    int d0 = (bid-BB)*8;
    __shared__ float s[128][9];
    #pragma unroll
    for(int p=0;p<4;p++){ int i = t + p*256; int c = i>>3, dd = i&7;
      s[c][dd] = vw[c*128 + d0 + dd]; }
    __syncthreads();
    #pragma unroll
    for(int p=0;p<4;p++){ int i = t + p*256; int dd = i>>7, c = i&127;
      wt[(size_t)(d0+dd)*128 + c] = f2bf(s[c][dd]); }
  } else if(bid < BB+32){
    int d0 = (bid-BB-16)*8;
    __shared__ float s[128][9];
    #pragma unroll
    for(int p=0;p<4;p++){ int i = t + p*256; int c = i>>3, dd = i&7;
      s[c][dd] = cw2[c*128 + d0 + dd]; }
    __syncthreads();
    #pragma unroll
    for(int p=0;p<4;p++){ int i = t + p*256; int dd = i>>7, c = i&127;
      cw2t[(size_t)(d0+dd)*128 + c] = f2bf(s[c][dd]); }
  } else if(bid < BB+32+76){
    __shared__ float tile[128][33];
    int idx = bid - (BB+32);
    int b = idx/38; int n0 = (idx%38)*32;
    for(int i=t;i<128*32;i+=256){ int c=i>>5, nn=i&31; int n=n0+nn;
      tile[c][nn] = (n<NQ)? iqf[((size_t)b*CC + c)*NQ + n] : 0.f; }
    __syncthreads();
    for(int i=t;i<32*128;i+=256){ int nn=i>>7, c=i&127;
      int n=n0+nn; if(n<NQ) x[((size_t)b*NQ+n)*128 + c] = tile[c][nn]; }
  } else {
    __shared__ float hid[4][128];
    int row0 = (bid - (BB+32+76))*4;
    int r = t>>7, d = t&127;
    #pragma unroll
    for(int rr=r; rr<4; rr+=2){
      int row = row0 + rr;
      float p0 = pos[row*2+0], p1 = pos[row*2+1];
      hid[rr][d] = fmaxf(p0*w1[d] + p1*w1[128+d] + b1[d], 0.f);
    }
    __syncthreads();
    #pragma unroll
    for(int rr=r; rr<4; rr+=2){
      float acc = b2[d];
      #pragma unroll 4
      for(int c=0;c<128;c++) acc += hid[rr][c]*w2[c*128 + d];
      qpe[(size_t)(row0+rr)*128+d] = acc;
    }
  }
}

// ---------------- kvpe via MFMA: hid MLP -> GEMM1 (cw2t) -> GEMM2 (wt) ----------------
__global__ void __launch_bounds__(256) k_kvpe2(
    const float* __restrict__ kpos,
    const float* __restrict__ cw1, const float* __restrict__ cb1,
    const unsigned short* __restrict__ cw2t, const float* __restrict__ cb2,
    const unsigned short* __restrict__ wt, const float* __restrict__ vb,
    unsigned short* __restrict__ kvpe){
  __shared__ unsigned short h_t[64][136];
  __shared__ unsigned short k_t[64][136];
  int t = threadIdx.x;
  int r0 = blockIdx.x*64;
  int lane = t&63, wave = t>>6;
  int fr = lane&15, kg = lane>>4;

  int p = t & 63;
  int d0 = p*2;
  float w1a0 = cw1[d0],     w1a1 = cw1[d0+1];
  float w1b0 = cw1[128+d0], w1b1 = cw1[128+d0+1];
  float b10 = cb1[d0], b11 = cb1[d0+1];
  #pragma unroll 4
  for(int k=0;k<16;k++){
    int r = wave + k*4;
    int row = r0 + r;
    float p0=0.f, p1=0.f;
    if(row < LTOT){ p0 = kpos[row*2]; p1 = kpos[row*2+1]; }
    float h0 = fmaxf(p0*w1a0 + p1*w1b0 + b10, 0.f);
    float h1 = fmaxf(p0*w1a1 + p1*w1b1 + b11, 0.f);
    *reinterpret_cast<unsigned*>(&h_t[r][d0]) = (unsigned)f2bf(h0) | ((unsigned)f2bf(h1)<<16);
  }
  __syncthreads();

  f32x4 acc[4][2];
  #pragma unroll
  for(int i=0;i<4;i++)
    #pragma unroll
    for(int j=0;j<2;j++) acc[i][j] = (f32x4)0.f;
  #pragma unroll
  for(int ck=0; ck<4; ck++){
    int c0 = ck*32;
    bf16x8 bfr[2], af[4];
    #pragma unroll
    for(int j=0;j<2;j++){ int d = wave*32 + j*16 + fr;
      bfr[j] = *reinterpret_cast<const bf16x8*>(cw2t + (size_t)d*128 + c0 + kg*8); }
    #pragma unroll
    for(int i=0;i<4;i++) af[i] = *reinterpret_cast<const bf16x8*>(&h_t[i*16 + fr][c0 + kg*8]);
    #pragma unroll
    for(int i=0;i<4;i++)
      #pragma unroll
      for(int j=0;j<2;j++)
        acc[i][j] = __builtin_amdgcn_mfma_f32_16x16x32_bf16(af[i], bfr[j], acc[i][j], 0, 0, 0);
  }
  #pragma unroll
  for(int i=0;i<4;i++){
    int rbase = i*16 + kg*4;
    #pragma unroll
    for(int j=0;j<2;j++){
      int d = wave*32 + j*16 + fr;
      float bv_ = cb2[d];
      #pragma unroll
      for(int r=0;r<4;r++) k_t[rbase + r][d] = f2bf(acc[i][j][r] + bv_);
    }
  }
  __syncthreads();

  #pragma unroll
  for(int i=0;i<4;i++)
    #pragma unroll
    for(int j=0;j<2;j++) acc[i][j] = (f32x4)0.f;
  #pragma unroll
  for(int ck=0; ck<4; ck++){
    int c0 = ck*32;
    bf16x8 bfr[2], af[4];
    #pragma unroll
    for(int j=0;j<2;j++){ int d = wave*32 + j*16 + fr;
      bfr[j] = *reinterpret_cast<const bf16x8*>(wt + (size_t)d*128 + c0 + kg*8); }
    #pragma unroll
    for(int i=0;i<4;i++) af[i] = *reinterpret_cast<const bf16x8*>(&k_t[i*16 + fr][c0 + kg*8]);
    #pragma unroll
    for(int i=0;i<4;i++)
      #pragma unroll
      for(int j=0;j<2;j++)
        acc[i][j] = __builtin_amdgcn_mfma_f32_16x16x32_bf16(af[i], bfr[j], acc[i][j], 0, 0, 0);
  }
  __syncthreads();
  unsigned short (*c_l)[136] = h_t;
  #pragma unroll
  for(int i=0;i<4;i++){
    int rbase = i*16 + kg*4;
    #pragma unroll
    for(int j=0;j<2;j++){
      int d = wave*32 + j*16 + fr;
      float bv_ = vb[d];
      #pragma unroll
      for(int r=0;r<4;r++) c_l[rbase + r][d] = f2bf(acc[i][j][r] + bv_);
    }
  }
  __syncthreads();
  #pragma unroll
  for(int p4=0;p4<4;p4++){
    int i = t + p4*256;
    int row = i>>4, seg = i&15;
    int glr = r0 + row;
    if(glr < LTOT){
      uint4 cu = *reinterpret_cast<const uint4*>(&c_l[row][seg*8]);
      *reinterpret_cast<uint4*>(kvpe + (size_t)glr*CC + seg*8) = cu;
    }
  }
}

// ---------------- value projection GEMM (MFMA bf16, 256l tile, 1KB-granule reads) ----------------
__global__ void __launch_bounds__(512) k_value7(
    const float* __restrict__ f0, const float* __restrict__ f1,
    const float* __restrict__ f2, const float* __restrict__ f3,
    const unsigned short* __restrict__ kvpe, const unsigned short* __restrict__ wt,
    unsigned short* __restrict__ value){
  __shared__ __align__(16) char smem[35840];
  float (*a_f)[265] = (float(*)[265])smem;                 // 32*265*4 = 33920 B
  unsigned short (*c_l)[136] = (unsigned short(*)[136])smem; // 128*136*2 = 34816 B
  int t = threadIdx.x;
  int bxy = blockIdx.x;
  int bv = bxy % 12;
  int bx = bxy / 12;
  int lvl, tile;
  if(bx < 88){ lvl=0; tile=bx; }
  else if(bx < 110){ lvl=1; tile=bx-88; }
  else if(bx < 116){ lvl=2; tile=bx-110; }
  else { lvl=3; tile=bx-116; }
  const int HW = (lvl==0)?22400:(lvl==1)?5600:(lvl==2)?1400:350;
  const int startL = (lvl==0)?0:(lvl==1)?22400:(lvl==2)?28000:29400;
  const float* feat = (lvl==0)?f0:(lvl==1)?f1:(lvl==2)?f2:f3;
  const float* fbase = feat + (size_t)bv*128*(size_t)HW;
  int l0 = tile*256;

  int lane = t&63, wave = t>>6;
  int lgrp = wave>>1, dgrp = wave&1;
  int fr = lane&15, kg = lane>>4;

  f32x4 acc[4][4];
  #pragma unroll
  for(int i=0;i<4;i++)
    #pragma unroll
    for(int j=0;j<4;j++) acc[i][j] = (f32x4)0.f;

  // per-thread load units: c = (t+p*512)>>6, lq = t&63 (same for all p since 512=8*64)
  int lq = t & 63;
  int cu_ = t >> 6;   // 0..7; unit p adds 8
  int gl4 = l0 + lq*4;

  for(int ck=0; ck<4; ck++){
    int c0 = ck*32;
    // 1KB-granule loads: wave = one c-row, 64 lanes x float4 = 256 consecutive floats
    float4 v[4];
    #pragma unroll
    for(int p=0;p<4;p++){
      int c = cu_ + p*8;
      const float* src = fbase + (size_t)(c0+c)*HW + gl4;
      if(gl4 + 4 <= HW){ v[p] = *reinterpret_cast<const float4*>(src); }
      else {
        float e0 = (gl4+0<HW)? src[0] : 0.f;
        float e1 = (gl4+1<HW)? src[1] : 0.f;
        float e2 = (gl4+2<HW)? src[2] : 0.f;
        float e3 = (gl4+3<HW)? src[3] : 0.f;
        v[p] = make_float4(e0,e1,e2,e3);
      }
    }
    __syncthreads();   // a_f free (prev chunk's reads done)
    #pragma unroll
    for(int p=0;p<4;p++){
      int c = cu_ + p*8;
      *reinterpret_cast<float4*>(&a_f[c][lq*4]) = v[p];
    }
    __syncthreads();
    // B fragments from L2-resident wt
    bf16x8 bfr[4];
    #pragma unroll
    for(int j=0;j<4;j++){
      int d = dgrp*64 + j*16 + fr;
      bfr[j] = *reinterpret_cast<const bf16x8*>(wt + (size_t)d*128 + c0 + kg*8);
    }
    // A fragments: 8 strided f32 reads + pack
    #pragma unroll
    for(int i=0;i<4;i++){
      int l = lgrp*64 + i*16 + fr;
      float a8[8];
      #pragma unroll
      for(int q=0;q<8;q++) a8[q] = a_f[kg*8+q][l];
      bf16x8 af;
      unsigned u0 = (unsigned)f2bf(a8[0]) | ((unsigned)f2bf(a8[1])<<16);
      unsigned u1 = (unsigned)f2bf(a8[2]) | ((unsigned)f2bf(a8[3])<<16);
      unsigned u2 = (unsigned)f2bf(a8[4]) | ((unsigned)f2bf(a8[5])<<16);
      unsigned u3 = (unsigned)f2bf(a8[6]) | ((unsigned)f2bf(a8[7])<<16);
      unsigned* ap = reinterpret_cast<unsigned*>(&af);
      ap[0]=u0; ap[1]=u1; ap[2]=u2; ap[3]=u3;
      #pragma unroll
      for(int j=0;j<4;j++)
        acc[i][j] = __builtin_amdgcn_mfma_f32_16x16x32_bf16(af, bfr[j], acc[i][j], 0, 0, 0);
    }
  }

  // epilogue: two 128-row halves through c_l staging
  #pragma unroll
  for(int hs=0; hs<2; hs++){
    __syncthreads();
    if((lgrp>>1) == hs){
      #pragma unroll
      for(int i=0;i<4;i++){
        int lrow = (lgrp&1)*64 + i*16 + kg*4;
        #pragma unroll
        for(int j=0;j<4;j++){
          int d = dgrp*64 + j*16 + fr;
          #pragma unroll
          for(int r=0;r<4;r++) c_l[lrow + r][d] = f2bf(acc[i][j][r]);
        }
      }
    }
    __syncthreads();
    #pragma unroll
    for(int p=0;p<4;p++){
      int i = t + p*512;
      int row = i>>4, seg = i&15;
      int glr = l0 + hs*128 + row;
      if(glr < HW){
        uint4 cu2 = *reinterpret_cast<const uint4*>(&c_l[row][seg*8]);
        const uint4 ku = *reinterpret_cast<const uint4*>(kvpe + (size_t)(startL+glr)*CC + seg*8);
        uint4 ou;
        ou.x = addbf2(cu2.x, ku.x); ou.y = addbf2(cu2.y, ku.y);
        ou.z = addbf2(cu2.z, ku.z); ou.w = addbf2(cu2.w, ku.w);
        *reinterpret_cast<uint4*>(value + ((size_t)bv*LTOT + startL + glr)*CC + seg*8) = ou;
      }
    }
  }
}

// ---------------- generic R-row batched matvec ----------------
template<int K, int N, int R, bool RELU>
__global__ void k_matvec(const float* __restrict__ in, const float* __restrict__ in2,
                         const float* __restrict__ W, const float* __restrict__ bias,
                         float* __restrict__ out, int nrows){
  int r0 = blockIdx.x*R; int d = threadIdx.x;
  __shared__ float s_in[R][K];
  for(int i=d;i<R*K;i+=N){
    int r=i/K, c=i%K; int row=r0+r;
    float v=0.f;
    if(row<nrows){ v = in[(size_t)row*K+c]; if(in2) v += in2[(size_t)row*K+c]; }
    s_in[r][c]=v;
  }
  __syncthreads();
  float acc[R];
  #pragma unroll
  for(int r=0;r<R;r++) acc[r]=bias[d];
  #pragma unroll 4
  for(int c=0;c<K;c++){ float wv = W[(size_t)c*N+d];
    #pragma unroll
    for(int r=0;r<R;r++) acc[r] += s_in[r][c]*wv; }
  #pragma unroll
  for(int r=0;r<R;r++){
    int row=r0+r;
    if(row<nrows){ float v=acc[r]; if(RELU) v=fmaxf(v,0.f); out[(size_t)row*N+d]=v; }
  }
}

// ---------------- bucketed self-attention ----------------
#define QT2 64
#define KT2 128
__global__ void __launch_bounds__(256) k_attn_v(const float* __restrict__ qkv,
        const int* __restrict__ order, const int* __restrict__ counts,
        float* __restrict__ att){
  int qt = blockIdx.x;
  int vh = blockIdx.y; int v = vh>>3, h = vh&7;
  int b = blockIdx.z;
  int C = counts[b*VV+v];
  int q0 = qt*QT2;
  if(q0 >= C) return;
  const int* ord = order + (size_t)(b*VV+v)*NQ;
  int t = threadIdx.x;
  __shared__ float q_s[QT2][17];
  __shared__ int qn_s[QT2];
  __shared__ float k_s[KT2][16];
  __shared__ float v_s[KT2][16];
  __shared__ float red[4][QT2][18];
  for(int i=t;i<QT2;i+=256){ int qi=q0+i; qn_s[i] = (qi<C)? ord[qi] : -1; }
  __syncthreads();
  for(int i=t;i<QT2*16;i+=256){ int r=i>>4,c=i&15; int n=qn_s[r];
    q_s[r][c] = (n>=0)? qkv[((size_t)b*NQ+n)*384 + h*16 + c] : 0.f; }
  int qi = t&63, sub = t>>6;
  float m = -1e30f, s = 0.f, acc[16];
  #pragma unroll
  for(int c=0;c<16;c++) acc[c]=0.f;
  for(int k0=0; k0<C; k0+=KT2){
    int kn = C-k0; if(kn>KT2) kn=KT2;
    __syncthreads();
    for(int i=t;i<KT2*16;i+=256){ int r=i>>4,c=i&15;
      float kv=0.f, vv=0.f;
      if(r<kn){ int n=ord[k0+r]; size_t base=((size_t)b*NQ+n)*384 + h*16 + c;
        kv = qkv[base+128]; vv = qkv[base+256]; }
      k_s[r][c]=kv; v_s[r][c]=vv; }
    __syncthreads();
    for(int mm=sub; mm<kn; mm+=4){
      float l=0.f;
      #pragma unroll
      for(int c=0;c<16;c++) l += q_s[qi][c]*k_s[mm][c];
      l *= 0.25f;
      float newm = fmaxf(m,l);
      float e = __expf(l - newm);
      if(newm > m){
        float rr = __expf(m - newm);
        s *= rr;
        #pragma unroll
        for(int c=0;c<16;c++) acc[c]*=rr;
        m = newm;
      }
      s += e;
      #pragma unroll
      for(int c=0;c<16;c++) acc[c] += e*v_s[mm][c];
    }
  }
  red[sub][qi][0]=m; red[sub][qi][1]=s;
  #pragma unroll
  for(int c=0;c<16;c++) red[sub][qi][2+c]=acc[c];
  __syncthreads();
  if(sub==0){
    int n = qn_s[qi];
    if(n>=0){
      float M=-1e30f;
      #pragma unroll
      for(int j=0;j<4;j++) M=fmaxf(M,red[j][qi][0]);
      float S=0.f; float o[16];
      #pragma unroll
      for(int c=0;c<16;c++) o[c]=0.f;
      #pragma unroll
      for(int j=0;j<4;j++){ float e=__expf(red[j][qi][0]-M); S += e*red[j][qi][1];
        #pragma unroll
        for(int c=0;c<16;c++) o[c] += e*red[j][qi][2+c]; }
      float inv = 1.f/S;
      #pragma unroll
      for(int c=0;c<16;c++) att[((size_t)b*NQ+n)*128 + h*16 + c] = o[c]*inv;
    }
  }
}

// ---------------- proj + residual + LN1 (qc = ln_out + qpe) ----------------
__global__ void k_proj_ln1(const float* __restrict__ in, const float* __restrict__ W,
                          const float* __restrict__ bias, const float* __restrict__ resid,
                          const float* __restrict__ g, const float* __restrict__ bb,
                          const float* __restrict__ qpe, float* __restrict__ xout,
                          float* __restrict__ qc){
  int r0 = blockIdx.x*8; int d = threadIdx.x;
  __shared__ float s_in[8][128];
  __shared__ float s_m[8][2][2];
  for(int i=d;i<8*128;i+=128){ int r=i>>7, c=i&127; s_in[r][c] = in[(size_t)(r0+r)*128 + c]; }
  __syncthreads();
  float acc[8];
  #pragma unroll
  for(int r=0;r<8;r++) acc[r]=bias[d];
  #pragma unroll 4
  for(int c=0;c<128;c++){ float wv = W[c*128+d];
    #pragma unroll
    for(int r=0;r<8;r++) acc[r] += s_in[r][c]*wv; }
  float v[8];
  int lane = d&63, wid = d>>6;
  #pragma unroll
  for(int r=0;r<8;r++){
    v[r] = acc[r] + resid[(size_t)(r0+r)*128 + d];
    float s1=v[r], s2=v[r]*v[r];
    for(int o=32;o>0;o>>=1){ s1 += __shfl_down(s1,o); s2 += __shfl_down(s2,o); }
    if(lane==0){ s_m[r][wid][0]=s1; s_m[r][wid][1]=s2; }
  }
  __syncthreads();
  #pragma unroll
  for(int r=0;r<8;r++){
    float S1=s_m[r][0][0]+s_m[r][1][0], S2=s_m[r][0][1]+s_m[r][1][1];
    float mean=S1*(1.f/128.f), var=S2*(1.f/128.f)-mean*mean;
    float rs=rsqrtf(var+1e-5f);
    float o=(v[r]-mean)*rs*g[d]+bb[d];
    xout[(size_t)(r0+r)*128+d]=o;
    qc[(size_t)(r0+r)*128+d]=o+qpe[(size_t)(r0+r)*128+d];
  }
}

// ---------------- fused: offset matvec (N=256) + attn-weight matvec + softmax ----------------
__global__ void k_off_aw(const float* __restrict__ qc,
                         const float* __restrict__ dow, const float* __restrict__ dob,
                         const float* __restrict__ daw, const float* __restrict__ dab,
                         float* __restrict__ offb, float* __restrict__ awb){
  int r0 = blockIdx.x*8; int t = threadIdx.x; // 384 threads
  __shared__ float s_in[8][128];
  __shared__ float s_aw[8][130];
  for(int i=t;i<8*128;i+=384){ int r=i>>7, c=i&127; s_in[r][c]=qc[(size_t)(r0+r)*128+c]; }
  __syncthreads();
  if(t < 256){
    int d = t;
    float acc[8];
    #pragma unroll
    for(int r=0;r<8;r++) acc[r]=dob[d];
    #pragma unroll 4
    for(int c=0;c<128;c++){ float wv = dow[(size_t)c*256+d];
      #pragma unroll
      for(int r=0;r<8;r++) acc[r] += s_in[r][c]*wv; }
    #pragma unroll
    for(int r=0;r<8;r++) offb[(size_t)(r0+r)*256+d]=acc[r];
  } else {
    int d = t - 256;
    float acc[8];
    #pragma unroll
    for(int r=0;r<8;r++) acc[r]=dab[d];
    #pragma unroll 4
    for(int c=0;c<128;c++){ float wv = daw[(size_t)c*128+d];
      #pragma unroll
      for(int r=0;r<8;r++) acc[r] += s_in[r][c]*wv; }
    #pragma unroll
    for(int r=0;r<8;r++) s_aw[r][d]=acc[r];
  }
  __syncthreads();
  if(t < 64){
    int r = t>>3, h = t&7;
    float mx=-1e30f;
    #pragma unroll
    for(int i=0;i<16;i++) mx = fmaxf(mx, s_aw[r][h*16+i]);
    float e[16]; float sm=0.f;
    #pragma unroll
    for(int i=0;i<16;i++){ e[i]=__expf(s_aw[r][h*16+i]-mx); sm+=e[i]; }
    float inv = 1.f/sm;
    #pragma unroll
    for(int i=0;i<16;i++) awb[(size_t)(r0+r)*128 + h*16+i] = e[i]*inv;
  }
}

// ---------------- deformable bilinear sampling ----------------
__global__ void k_sample(const float* __restrict__ qpos, const int* __restrict__ view,
                         const float* __restrict__ offb, const float* __restrict__ awb,
                         const unsigned short* __restrict__ value, float* __restrict__ ca){
  int n = blockIdx.x, b = blockIdx.y;
  size_t row = (size_t)b*NQ + n;
  int t = threadIdx.x;
  int h = t>>4, lp = t&15, lvl = lp>>2;
  float rx = sigm(qpos[row*2]), ry = sigm(qpos[row*2+1]);
  int vw = view[row];
  int w = c_W[lvl], hh = c_H[lvl];
  float ox = offb[row*256 + t*2], oy = offb[row*256 + t*2+1];
  float a = awb[row*128 + t];
  float lx = rx*(float)w + ox - 0.5f;
  float ly = ry*(float)hh + oy - 0.5f;
  float x0f = floorf(lx), y0f = floorf(ly);
  float fx = lx - x0f, fy = ly - y0f;
  int x0 = (int)x0f, y0 = (int)y0f;
  float samp[16];
  #pragma unroll
  for(int c=0;c<16;c++) samp[c]=0.f;
  size_t brow = ((size_t)(b*VV + vw))*LTOT + c_S[lvl];
  #pragma unroll
  for(int dy=0;dy<2;dy++){
    #pragma unroll
    for(int dx=0;dx<2;dx++){
      int xi=x0+dx, yi=y0+dy;
      if(xi<0||xi>=w||yi<0||yi>=hh) continue;
      float wt = (dx?fx:(1.f-fx))*(dy?fy:(1.f-fy));
      const uint4* vp = reinterpret_cast<const uint4*>(value + (brow + (size_t)yi*w + xi)*CC + h*16);
      uint4 u0 = vp[0], u1 = vp[1];
      samp[0] += wt*bflo(u0.x); samp[1] += wt*bfhi(u0.x);
      samp[2] += wt*bflo(u0.y); samp[3] += wt*bfhi(u0.y);
      samp[4] += wt*bflo(u0.z); samp[5] += wt*bfhi(u0.z);
      samp[6] += wt*bflo(u0.w); samp[7] += wt*bfhi(u0.w);
      samp[8] += wt*bflo(u1.x); samp[9] += wt*bfhi(u1.x);
      samp[10]+= wt*bflo(u1.y); samp[11]+= wt*bfhi(u1.y);
      samp[12]+= wt*bflo(u1.z); samp[13]+= wt*bfhi(u1.z);
      samp[14]+= wt*bflo(u1.w); samp[15]+= wt*bfhi(u1.w);
    }
  }
  __shared__ float sred[128][17];
  #pragma unroll
  for(int c=0;c<16;c++) sred[t][c] = a*samp[c];
  __syncthreads();
  int h2=t>>4, c2=t&15;
  float sum=0.f;
  #pragma unroll
  for(int j=0;j<16;j++) sum += sred[h2*16+j][c2];
  ca[row*128 + t] = sum;
}

// ---------------- fused tail: proj_ln2 + FFN1 + FFN2/LN3 + head ----------------
__global__ void __launch_bounds__(128) k_tail(
    const float* __restrict__ ca, const float* __restrict__ dOw, const float* __restrict__ dOb,
    const float* __restrict__ xres,
    const float* __restrict__ ln2_g, const float* __restrict__ ln2_b,
    const float* __restrict__ fw1, const float* __restrict__ fb1,
    const float* __restrict__ fw2, const float* __restrict__ fb2,
    const float* __restrict__ ln3_g, const float* __restrict__ ln3_b,
    const float* __restrict__ pw1, const float* __restrict__ pb1,
    const float* __restrict__ pw2, const float* __restrict__ pb2,
    const int* __restrict__ counts, const int* __restrict__ view,
    const float* __restrict__ pos, float* __restrict__ dout){
  int r0 = blockIdx.x*4; int d = threadIdx.x;  // 128 threads
  __shared__ float s_a[4][256];
  __shared__ float s_x[4][128];
  __shared__ float s_m[4][2][2];
  __shared__ float s_res[4][6];
  int lane = d&63, wid = d>>6;

  #pragma unroll
  for(int r=0;r<4;r++) s_a[r][d] = ca[(size_t)(r0+r)*128 + d];
  __syncthreads();

  float acc[4];
  #pragma unroll
  for(int r=0;r<4;r++) acc[r]=dOb[d];
  #pragma unroll 4
  for(int c=0;c<128;c++){ float wv = dOw[c*128+d];
    #pragma unroll
    for(int r=0;r<4;r++) acc[r] += s_a[r][c]*wv; }
  float v[4];
  #pragma unroll
  for(int r=0;r<4;r++){
    v[r] = acc[r] + xres[(size_t)(r0+r)*128 + d];
    float s1=v[r], s2=v[r]*v[r];
    for(int o=32;o>0;o>>=1){ s1 += __shfl_down(s1,o); s2 += __shfl_down(s2,o); }
    if(lane==0){ s_m[r][wid][0]=s1; s_m[r][wid][1]=s2; }
  }
  __syncthreads();
  #pragma unroll
  for(int r=0;r<4;r++){
    float S1=s_m[r][0][0]+s_m[r][1][0], S2=s_m[r][0][1]+s_m[r][1][1];
    float mean=S1*(1.f/128.f), var=S2*(1.f/128.f)-mean*mean;
    float rs=rsqrtf(var+1e-5f);
    s_x[r][d]=(v[r]-mean)*rs*ln2_g[d]+ln2_b[d];
  }
  __syncthreads();

  float a2a[4], a2b[4];
  #pragma unroll
  for(int r=0;r<4;r++){ a2a[r]=fb1[d]; a2b[r]=fb1[d+128]; }
  #pragma unroll 4
  for(int c=0;c<128;c++){ float w0 = fw1[c*256+d], w1_ = fw1[c*256+d+128];
    #pragma unroll
    for(int r=0;r<4;r++){ float xv = s_x[r][c]; a2a[r] += xv*w0; a2b[r] += xv*w1_; } }
  __syncthreads();
  #pragma unroll
  for(int r=0;r<4;r++){ s_a[r][d]=fmaxf(a2a[r],0.f); s_a[r][d+128]=fmaxf(a2b[r],0.f); }
  __syncthreads();

  float a3[4];
  #pragma unroll
  for(int r=0;r<4;r++) a3[r]=fb2[d];
  #pragma unroll 4
  for(int c=0;c<256;c++){ float wv = fw2[c*128+d];
    #pragma unroll
    for(int r=0;r<4;r++) a3[r] += s_a[r][c]*wv; }
  #pragma unroll
  for(int r=0;r<4;r++){
    v[r] = a3[r] + s_x[r][d];
    float s1=v[r], s2=v[r]*v[r];
    for(int o=32;o>0;o>>=1){ s1 += __shfl_down(s1,o); s2 += __shfl_down(s2,o); }
    if(lane==0){ s_m[r][wid][0]=s1; s_m[r][wid][1]=s2; }
  }
  __syncthreads();
  #pragma unroll
  for(int r=0;r<4;r++){
    float S1=s_m[r][0][0]+s_m[r][1][0], S2=s_m[r][0][1]+s_m[r][1][1];
    float mean=S1*(1.f/128.f), var=S2*(1.f/128.f)-mean*mean;
    float rs=rsqrtf(var+1e-5f);
    float o=(v[r]-mean)*rs*ln3_g[d]+ln3_b[d];
    int row=r0+r; int b=row/NQ, n=row%NQ;
    bool val = counts[b*VV + view[row]] > 1;
    float oz = val ? o : 0.f;
    s_x[r][d]=oz;
    dout[((size_t)b*CC + d)*NQ + n]=oz;
  }
  __syncthreads();

  float a4[4];
  #pragma unroll
  for(int r=0;r<4;r++) a4[r]=pb1[d];
  #pragma unroll 4
  for(int c=0;c<128;c++){ float wv = pw1[c*128+d];
    #pragma unroll
    for(int r=0;r<4;r++) a4[r] += s_x[r][c]*wv; }
  #pragma unroll
  for(int r=0;r<4;r++) s_a[r][d]=fmaxf(a4[r],0.f);
  __syncthreads();

  if(d < 24){
    int r = d/6, o = d%6;
    float a5 = pb2[o];
    #pragma unroll 4
    for(int c=0;c<128;c++) a5 += s_a[r][c]*pw2[c*6+o];
    s_res[r][o] = a5;
  }
  __syncthreads();
  if(d < 4){
    int r = d; int row = r0+r; int b=row/NQ, n=row%NQ;
    const int O1 = BB*CC*NQ;
    const int O2 = O1 + BB*NQ*2;
    const int O3 = O2 + BB*2*NQ;
    const int O4 = O3 + BB*4*NQ;
    float p0=pos[row*2], p1=pos[row*2+1];
    float cr0 = s_res[r][0]+p0, cr1 = s_res[r][1]+p1;
    dout[O1 + row*2]   = cr0;
    dout[O1 + row*2+1] = cr1;
    float cen0 = sigm(cr0), cen1 = sigm(cr1);
    dout[O2 + (b*2+0)*NQ + n] = cen0;
    dout[O2 + (b*2+1)*NQ + n] = cen1;
    float f0=sigm(s_res[r][2]), f1=sigm(s_res[r][3]), f2=sigm(s_res[r][4]), f3=sigm(s_res[r][5]);
    dout[O3 + (b*4+0)*NQ + n] = f0;
    dout[O3 + (b*4+1)*NQ + n] = f1;
    dout[O3 + (b*4+2)*NQ + n] = f2;
    dout[O3 + (b*4+3)*NQ + n] = f3;
    float bw=f0+f2, bh=f1+f3;
    float cx=(2.f*cen0 - f0 + f2)*0.5f;
    float cy=(2.f*cen1 - f1 + f3)*0.5f;
    dout[O4 + (b*4+0)*NQ + n] = cx;
    dout[O4 + (b*4+1)*NQ + n] = cy;
    dout[O4 + (b*4+2)*NQ + n] = bw;
    dout[O4 + (b*4+3)*NQ + n] = bh;
  }
}

extern "C" void kernel_launch(void* const* d_in, const int* in_sizes, int n_in,
                              void* d_out, int out_size, void* d_ws, size_t ws_size,
                              hipStream_t stream){
  (void)in_sizes; (void)n_in; (void)out_size; (void)ws_size;
  const float* in_iqf  = (const float*)d_in[0];
  const float* in_qpos = (const float*)d_in[1];
  const float* in_feat[4] = {(const float*)d_in[2],(const float*)d_in[3],(const float*)d_in[4],(const float*)d_in[5]};
  const float* in_kpos = (const float*)d_in[6];
  const float* sp_w1=(const float*)d_in[7], *sp_b1=(const float*)d_in[8], *sp_w2=(const float*)d_in[9], *sp_b2=(const float*)d_in[10];
  const float* cp_w1=(const float*)d_in[11], *cp_b1=(const float*)d_in[12], *cp_w2=(const float*)d_in[13], *cp_b2=(const float*)d_in[14];
  const float* sa_wqkv=(const float*)d_in[15], *sa_bqkv=(const float*)d_in[16], *sa_wo=(const float*)d_in[17], *sa_bo=(const float*)d_in[18];
  const float* ln1_g=(const float*)d_in[19], *ln1_b=(const float*)d_in[20];
  const float* dvw=(const float*)d_in[21], *dvb=(const float*)d_in[22];
  const float* dow=(const float*)d_in[23], *dob=(const float*)d_in[24];
  const float* daw=(const float*)d_in[25], *dab=(const float*)d_in[26];
  const float* dOw=(const float*)d_in[27], *dOb=(const float*)d_in[28];
  const float* ln2_g=(const float*)d_in[29], *ln2_b=(const float*)d_in[30];
  const float* fw1=(const float*)d_in[31], *fb1=(const float*)d_in[32], *fw2=(const float*)d_in[33], *fb2=(const float*)d_in[34];
  const float* ln3_g=(const float*)d_in[35], *ln3_b=(const float*)d_in[36];
  const float* pw1=(const float*)d_in[37], *pb1=(const float*)d_in[38], *pw2=(const float*)d_in[39], *pb2=(const float*)d_in[40];
  const int* in_view = (const int*)d_in[41];
  float* out = (float*)d_out;

  char* ws = (char*)d_ws;
  unsigned short* value = (unsigned short*)ws;                       // 91,392,000 B
  unsigned short* kvpe  = (unsigned short*)(ws + 91392000);          //  7,616,000 B
  float* f = (float*)(ws + 91392000 + 7616000);
  float* qpe  = f;               // 307200
  float* x    = f + 307200;      // 307200
  float* qkv  = f + 614400;      // 921600
  float* att  = f + 1536000;     // 307200
  float* qc   = f + 1843200;     // 307200
  float* offb = f + 2150400;     // 614400
  float* awb  = f + 2764800;     // 307200
  float* ca   = f + 3072000;     // 307200
  int* counts = (int*)(f + 4300800);   // 12 ints
  int* order  = (int*)(f + 4300816);   // B*VV*NQ = 14400 ints
  unsigned short* wtb   = (unsigned short*)(f + 4315216);  // 32768 B
  unsigned short* cw2tb = (unsigned short*)(f + 4323408);  // 32768 B

  k_misc<<<dim3(BB+32+76+600),dim3(256),0,stream>>>(in_view,order,counts,dvw,wtb,
      cp_w2,cw2tb,in_iqf,x,in_qpos,sp_w1,sp_b1,sp_w2,sp_b2,qpe);
  k_kvpe2<<<dim3((LTOT+63)/64),dim3(256),0,stream>>>(in_kpos,cp_w1,cp_b1,cw2tb,cp_b2,wtb,dvb,kvpe);
  k_value7<<<dim3(118*12),dim3(512),0,stream>>>(in_feat[0],in_feat[1],in_feat[2],in_feat[3],kvpe,wtb,value);
  k_matvec<128,384,8,false><<<dim3(NROWS/8),dim3(384),0,stream>>>(x,qpe,sa_wqkv,sa_bqkv,qkv,NROWS);
  k_attn_v<<<dim3((NQ+QT2-1)/QT2, VV*HH, BB),dim3(256),0,stream>>>(qkv,order,counts,att);
  k_proj_ln1<<<dim3(NROWS/8),dim3(128),0,stream>>>(att,sa_wo,sa_bo,x,ln1_g,ln1_b,qpe,x,qc);
  k_off_aw<<<dim3(NROWS/8),dim3(384),0,stream>>>(qc,dow,dob,daw,dab,offb,awb);
  k_sample<<<dim3(NQ,BB),dim3(128),0,stream>>>(in_qpos,in_view,offb,awb,value,ca);
  k_tail<<<dim3(NROWS/4),dim3(128),0,stream>>>(ca,dOw,dOb,x,ln2_g,ln2_b,
      fw1,fb1,fw2,fb2,ln3_g,ln3_b,pw1,pb1,pw2,pb2,counts,in_view,in_qpos,out);
}

// Round 10
// 225.954 us; speedup vs baseline: 1.2092x; 1.2092x over previous
//
#include <hip/hip_runtime.h>
#include <hip/hip_bf16.h>
#include <math.h>

#define DEV __device__ __forceinline__

#define BB 2
#define VV 6
#define CC 128
#define NQ 1200
#define HH 8
#define PTSN 4
#define FFND 256
#define LVLSN 4
#define LTOT 29750
#define NROWS (BB*NQ)

__constant__ int c_W[4] = {200,100,50,25};
__constant__ int c_H[4] = {112,56,28,14};
__constant__ int c_S[4] = {0,22400,28000,29400};

DEV float bflo(unsigned u){ union{unsigned i; float f;}x; x.i = u<<16; return x.f; }
DEV float bfhi(unsigned u){ union{unsigned i; float f;}x; x.i = u&0xffff0000u; return x.f; }
DEV unsigned short f2bf(float f){ union{float f; unsigned i;}x; x.f=f; unsigned i=x.i;
  return (unsigned short)((i + 0x7fffu + ((i>>16)&1u))>>16); }
DEV unsigned addbf2(unsigned a, unsigned b){
  float lo = bflo(a)+bflo(b); float hi = bfhi(a)+bfhi(b);
  return (unsigned)f2bf(lo) | ((unsigned)f2bf(hi)<<16);
}
DEV float sigm(float z){ return 1.f/(1.f+__expf(-z)); }

typedef __attribute__((ext_vector_type(8))) short bf16x8;
typedef __attribute__((ext_vector_type(4))) float f32x4;

// ---------------- fused setup: bucket(2) + wt(16) + cw2t(16) + xpose(76) + qpe(600) ----------------
__global__ void k_misc(const int* __restrict__ view, int* __restrict__ order,
                       int* __restrict__ counts,
                       const float* __restrict__ vw, unsigned short* __restrict__ wt,
                       const float* __restrict__ cw2, unsigned short* __restrict__ cw2t,
                       const float* __restrict__ iqf, float* __restrict__ x,
                       const float* __restrict__ pos,
                       const float* __restrict__ w1, const float* __restrict__ b1,
                       const float* __restrict__ w2, const float* __restrict__ b2,
                       float* __restrict__ qpe){
  int bid = blockIdx.x;
  int t = threadIdx.x;
  if(bid < BB){
    if(t < 64){
      int b = bid; int lane = t;
      int base0=0,base1=0,base2=0,base3=0,base4=0,base5=0;
      for(int c0=0;c0<NQ;c0+=64){
        int n = c0 + lane;
        int v = (n<NQ) ? view[b*NQ+n] : -1;
        unsigned long long lower = (lane==63)? 0x7fffffffffffffffull : ((1ull<<lane)-1ull);
        #define BUCKET_STEP(VVV, BASE) { \
          unsigned long long mk = __ballot(v==VVV); \
          if(v==VVV){ int r = BASE + __popcll(mk & lower); order[(b*VV+VVV)*NQ + r] = n; } \
          BASE += __popcll(mk); }
        BUCKET_STEP(0, base0) BUCKET_STEP(1, base1) BUCKET_STEP(2, base2)
        BUCKET_STEP(3, base3) BUCKET_STEP(4, base4) BUCKET_STEP(5, base5)
        #undef BUCKET_STEP
      }
      if(lane==0){
        counts[b*VV+0]=base0; counts[b*VV+1]=base1; counts[b*VV+2]=base2;
        counts[b*VV+3]=base3; counts[b*VV+4]=base4; counts[b*VV+5]=base5;
      }
    }
  } else if(bid < BB+16){
    int d0 = (bid-BB)*8;
    __shared__ float s[128][9];
    #pragma unroll
    for(int p=0;p<4;p++){ int i = t + p*256; int c = i>>3, dd = i&7;
      s[c][dd] = vw[c*128 + d0 + dd]; }
    __syncthreads();
    #pragma unroll
    for(int p=0;p<4;p++){ int i = t + p*256; int dd = i>>7, c = i&127;
      wt[(size_t)(d0+dd)*128 + c] = f2bf(s[c][dd]); }
  } else if(bid < BB+32){
    int d0 = (bid-BB-16)*8;
    __shared__ float s[128][9];
    #pragma unroll
    for(int p=0;p<4;p++){ int i = t + p*256; int c = i>>3, dd = i&7;
      s[c][dd] = cw2[c*128 + d0 + dd]; }
    __syncthreads();
    #pragma unroll
    for(int p=0;p<4;p++){ int i = t + p*256; int dd = i>>7, c = i&127;
      cw2t[(size_t)(d0+dd)*128 + c] = f2bf(s[c][dd]); }
  } else if(bid < BB+32+76){
    __shared__ float tile[128][33];
    int idx = bid - (BB+32);
    int b = idx/38; int n0 = (idx%38)*32;
    for(int i=t;i<128*32;i+=256){ int c=i>>5, nn=i&31; int n=n0+nn;
      tile[c][nn] = (n<NQ)? iqf[((size_t)b*CC + c)*NQ + n] : 0.f; }
    __syncthreads();
    for(int i=t;i<32*128;i+=256){ int nn=i>>7, c=i&127;
      int n=n0+nn; if(n<NQ) x[((size_t)b*NQ+n)*128 + c] = tile[c][nn]; }
  } else {
    __shared__ float hid[4][128];
    int row0 = (bid - (BB+32+76))*4;
    int r = t>>7, d = t&127;
    #pragma unroll
    for(int rr=r; rr<4; rr+=2){
      int row = row0 + rr;
      float p0 = pos[row*2+0], p1 = pos[row*2+1];
      hid[rr][d] = fmaxf(p0*w1[d] + p1*w1[128+d] + b1[d], 0.f);
    }
    __syncthreads();
    #pragma unroll
    for(int rr=r; rr<4; rr+=2){
      float acc = b2[d];
      #pragma unroll 4
      for(int c=0;c<128;c++) acc += hid[rr][c]*w2[c*128 + d];
      qpe[(size_t)(row0+rr)*128+d] = acc;
    }
  }
}

// ---------------- kvpe via MFMA: hid MLP -> GEMM1 (cw2t) -> GEMM2 (wt) ----------------
__global__ void __launch_bounds__(256) k_kvpe2(
    const float* __restrict__ kpos,
    const float* __restrict__ cw1, const float* __restrict__ cb1,
    const unsigned short* __restrict__ cw2t, const float* __restrict__ cb2,
    const unsigned short* __restrict__ wt, const float* __restrict__ vb,
    unsigned short* __restrict__ kvpe){
  __shared__ unsigned short h_t[64][136];
  __shared__ unsigned short k_t[64][136];
  int t = threadIdx.x;
  int r0 = blockIdx.x*64;
  int lane = t&63, wave = t>>6;
  int fr = lane&15, kg = lane>>4;

  int p = t & 63;
  int d0 = p*2;
  float w1a0 = cw1[d0],     w1a1 = cw1[d0+1];
  float w1b0 = cw1[128+d0], w1b1 = cw1[128+d0+1];
  float b10 = cb1[d0], b11 = cb1[d0+1];
  #pragma unroll 4
  for(int k=0;k<16;k++){
    int r = wave + k*4;
    int row = r0 + r;
    float p0=0.f, p1=0.f;
    if(row < LTOT){ p0 = kpos[row*2]; p1 = kpos[row*2+1]; }
    float h0 = fmaxf(p0*w1a0 + p1*w1b0 + b10, 0.f);
    float h1 = fmaxf(p0*w1a1 + p1*w1b1 + b11, 0.f);
    *reinterpret_cast<unsigned*>(&h_t[r][d0]) = (unsigned)f2bf(h0) | ((unsigned)f2bf(h1)<<16);
  }
  __syncthreads();

  f32x4 acc[4][2];
  #pragma unroll
  for(int i=0;i<4;i++)
    #pragma unroll
    for(int j=0;j<2;j++) acc[i][j] = (f32x4)0.f;
  #pragma unroll
  for(int ck=0; ck<4; ck++){
    int c0 = ck*32;
    bf16x8 bfr[2], af[4];
    #pragma unroll
    for(int j=0;j<2;j++){ int d = wave*32 + j*16 + fr;
      bfr[j] = *reinterpret_cast<const bf16x8*>(cw2t + (size_t)d*128 + c0 + kg*8); }
    #pragma unroll
    for(int i=0;i<4;i++) af[i] = *reinterpret_cast<const bf16x8*>(&h_t[i*16 + fr][c0 + kg*8]);
    #pragma unroll
    for(int i=0;i<4;i++)
      #pragma unroll
      for(int j=0;j<2;j++)
        acc[i][j] = __builtin_amdgcn_mfma_f32_16x16x32_bf16(af[i], bfr[j], acc[i][j], 0, 0, 0);
  }
  #pragma unroll
  for(int i=0;i<4;i++){
    int rbase = i*16 + kg*4;
    #pragma unroll
    for(int j=0;j<2;j++){
      int d = wave*32 + j*16 + fr;
      float bv_ = cb2[d];
      #pragma unroll
      for(int r=0;r<4;r++) k_t[rbase + r][d] = f2bf(acc[i][j][r] + bv_);
    }
  }
  __syncthreads();

  #pragma unroll
  for(int i=0;i<4;i++)
    #pragma unroll
    for(int j=0;j<2;j++) acc[i][j] = (f32x4)0.f;
  #pragma unroll
  for(int ck=0; ck<4; ck++){
    int c0 = ck*32;
    bf16x8 bfr[2], af[4];
    #pragma unroll
    for(int j=0;j<2;j++){ int d = wave*32 + j*16 + fr;
      bfr[j] = *reinterpret_cast<const bf16x8*>(wt + (size_t)d*128 + c0 + kg*8); }
    #pragma unroll
    for(int i=0;i<4;i++) af[i] = *reinterpret_cast<const bf16x8*>(&k_t[i*16 + fr][c0 + kg*8]);
    #pragma unroll
    for(int i=0;i<4;i++)
      #pragma unroll
      for(int j=0;j<2;j++)
        acc[i][j] = __builtin_amdgcn_mfma_f32_16x16x32_bf16(af[i], bfr[j], acc[i][j], 0, 0, 0);
  }
  __syncthreads();
  unsigned short (*c_l)[136] = h_t;
  #pragma unroll
  for(int i=0;i<4;i++){
    int rbase = i*16 + kg*4;
    #pragma unroll
    for(int j=0;j<2;j++){
      int d = wave*32 + j*16 + fr;
      float bv_ = vb[d];
      #pragma unroll
      for(int r=0;r<4;r++) c_l[rbase + r][d] = f2bf(acc[i][j][r] + bv_);
    }
  }
  __syncthreads();
  #pragma unroll
  for(int p4=0;p4<4;p4++){
    int i = t + p4*256;
    int row = i>>4, seg = i&15;
    int glr = r0 + row;
    if(glr < LTOT){
      uint4 cu = *reinterpret_cast<const uint4*>(&c_l[row][seg*8]);
      *reinterpret_cast<uint4*>(kvpe + (size_t)glr*CC + seg*8) = cu;
    }
  }
}

// ---------------- merged: qkv matvec (blocks 0..299) + value GEMM (blocks 300..5891) ----------------
#define QKVB 300
__global__ void __launch_bounds__(256) k_value_qkv(
    const float* __restrict__ f0, const float* __restrict__ f1,
    const float* __restrict__ f2, const float* __restrict__ f3,
    const unsigned short* __restrict__ kvpe, const unsigned short* __restrict__ wt,
    unsigned short* __restrict__ value,
    const float* __restrict__ x, const float* __restrict__ qpe,
    const float* __restrict__ sa_wqkv, const float* __restrict__ sa_bqkv,
    float* __restrict__ qkv){
  __shared__ unsigned short a_t[64][136];
  __shared__ float s_q[8][128];
  int t = threadIdx.x;
  int bid = blockIdx.x;
  if(bid < QKVB){
    // ---- qkv matvec: 8 rows, out width 384 ----
    int r0 = bid*8;
    for(int i=t;i<1024;i+=256){ int r=i>>7, c=i&127;
      size_t row = (size_t)(r0+r);
      s_q[r][c] = x[row*128+c] + qpe[row*128+c]; }
    __syncthreads();
    for(int d=t; d<384; d+=256){
      float acc[8];
      #pragma unroll
      for(int r=0;r<8;r++) acc[r]=sa_bqkv[d];
      #pragma unroll 4
      for(int c=0;c<128;c++){ float wv = sa_wqkv[c*384+d];
        #pragma unroll
        for(int r=0;r<8;r++) acc[r] += s_q[r][c]*wv; }
      #pragma unroll
      for(int r=0;r<8;r++) qkv[(size_t)(r0+r)*384+d]=acc[r];
    }
    return;
  }
  // ---- value GEMM (k_value6 core) ----
  int bxy = bid - QKVB;
  int bv = bxy % 12;
  int bx = bxy / 12;
  int lvl, tile;
  if(bx < 350){ lvl=0; tile=bx; }
  else if(bx < 438){ lvl=1; tile=bx-350; }
  else if(bx < 460){ lvl=2; tile=bx-438; }
  else { lvl=3; tile=bx-460; }
  const int HW = (lvl==0)?22400:(lvl==1)?5600:(lvl==2)?1400:350;
  const int startL = (lvl==0)?0:(lvl==1)?22400:(lvl==2)?28000:29400;
  const float* feat = (lvl==0)?f0:(lvl==1)?f1:(lvl==2)?f2:f3;
  const float* fbase = feat + (size_t)bv*128*(size_t)HW;
  int l0 = tile*64;

  int lane = t&63, wave = t>>6;
  int fr = lane&15, kg = lane>>4;

  int l_u = t & 63, oct0 = t>>6;
  int gl = l0 + l_u; bool ok = (gl < HW);
  const float* fcol = fbase + (size_t)(oct0*8)*HW + (ok ? gl : 0);

  float v32[4][8];
  #pragma unroll
  for(int q=0;q<4;q++)
    #pragma unroll
    for(int j=0;j<8;j++)
      v32[q][j] = ok ? fcol[(size_t)(q*32+j)*HW] : 0.f;

  #pragma unroll
  for(int q=0;q<4;q++){
    uint4 u;
    u.x = (unsigned)f2bf(v32[q][0]) | ((unsigned)f2bf(v32[q][1])<<16);
    u.y = (unsigned)f2bf(v32[q][2]) | ((unsigned)f2bf(v32[q][3])<<16);
    u.z = (unsigned)f2bf(v32[q][4]) | ((unsigned)f2bf(v32[q][5])<<16);
    u.w = (unsigned)f2bf(v32[q][6]) | ((unsigned)f2bf(v32[q][7])<<16);
    *reinterpret_cast<uint4*>(&a_t[l_u][oct0*8 + q*32]) = u;
  }
  __syncthreads();

  f32x4 acc[4][2];
  #pragma unroll
  for(int i=0;i<4;i++)
    #pragma unroll
    for(int j=0;j<2;j++) acc[i][j] = (f32x4)0.f;

  #pragma unroll
  for(int ck=0; ck<4; ck++){
    int c0 = ck*32;
    bf16x8 bfr[2];
    #pragma unroll
    for(int j=0;j<2;j++){
      int d = wave*32 + j*16 + fr;
      bfr[j] = *reinterpret_cast<const bf16x8*>(wt + (size_t)d*128 + c0 + kg*8);
    }
    bf16x8 af[4];
    #pragma unroll
    for(int i=0;i<4;i++) af[i] = *reinterpret_cast<const bf16x8*>(&a_t[i*16 + fr][c0 + kg*8]);
    #pragma unroll
    for(int i=0;i<4;i++)
      #pragma unroll
      for(int j=0;j<2;j++)
        acc[i][j] = __builtin_amdgcn_mfma_f32_16x16x32_bf16(af[i], bfr[j], acc[i][j], 0, 0, 0);
  }

  __syncthreads();
  unsigned short (*c_l)[136] = a_t;
  #pragma unroll
  for(int i=0;i<4;i++){
    int rbase = i*16 + kg*4;
    #pragma unroll
    for(int j=0;j<2;j++){
      int d = wave*32 + j*16 + fr;
      #pragma unroll
      for(int r=0;r<4;r++) c_l[rbase + r][d] = f2bf(acc[i][j][r]);
    }
  }
  __syncthreads();
  #pragma unroll
  for(int p=0;p<4;p++){
    int i = t + p*256;
    int row = i>>4, seg = i&15;
    int glr = l0 + row;
    if(glr < HW){
      uint4 cu = *reinterpret_cast<const uint4*>(&c_l[row][seg*8]);
      const uint4 ku = *reinterpret_cast<const uint4*>(kvpe + (size_t)(startL+glr)*CC + seg*8);
      uint4 ou;
      ou.x = addbf2(cu.x, ku.x); ou.y = addbf2(cu.y, ku.y);
      ou.z = addbf2(cu.z, ku.z); ou.w = addbf2(cu.w, ku.w);
      *reinterpret_cast<uint4*>(value + ((size_t)bv*LTOT + startL + glr)*CC + seg*8) = ou;
    }
  }
}

// ---------------- bucketed self-attention ----------------
#define QT2 64
#define KT2 128
__global__ void __launch_bounds__(256) k_attn_v(const float* __restrict__ qkv,
        const int* __restrict__ order, const int* __restrict__ counts,
        float* __restrict__ att){
  int qt = blockIdx.x;
  int vh = blockIdx.y; int v = vh>>3, h = vh&7;
  int b = blockIdx.z;
  int C = counts[b*VV+v];
  int q0 = qt*QT2;
  if(q0 >= C) return;
  const int* ord = order + (size_t)(b*VV+v)*NQ;
  int t = threadIdx.x;
  __shared__ float q_s[QT2][17];
  __shared__ int qn_s[QT2];
  __shared__ float k_s[KT2][16];
  __shared__ float v_s[KT2][16];
  __shared__ float red[4][QT2][18];
  for(int i=t;i<QT2;i+=256){ int qi=q0+i; qn_s[i] = (qi<C)? ord[qi] : -1; }
  __syncthreads();
  for(int i=t;i<QT2*16;i+=256){ int r=i>>4,c=i&15; int n=qn_s[r];
    q_s[r][c] = (n>=0)? qkv[((size_t)b*NQ+n)*384 + h*16 + c] : 0.f; }
  int qi = t&63, sub = t>>6;
  float m = -1e30f, s = 0.f, acc[16];
  #pragma unroll
  for(int c=0;c<16;c++) acc[c]=0.f;
  for(int k0=0; k0<C; k0+=KT2){
    int kn = C-k0; if(kn>KT2) kn=KT2;
    __syncthreads();
    for(int i=t;i<KT2*16;i+=256){ int r=i>>4,c=i&15;
      float kv=0.f, vv=0.f;
      if(r<kn){ int n=ord[k0+r]; size_t base=((size_t)b*NQ+n)*384 + h*16 + c;
        kv = qkv[base+128]; vv = qkv[base+256]; }
      k_s[r][c]=kv; v_s[r][c]=vv; }
    __syncthreads();
    for(int mm=sub; mm<kn; mm+=4){
      float l=0.f;
      #pragma unroll
      for(int c=0;c<16;c++) l += q_s[qi][c]*k_s[mm][c];
      l *= 0.25f;
      float newm = fmaxf(m,l);
      float e = __expf(l - newm);
      if(newm > m){
        float rr = __expf(m - newm);
        s *= rr;
        #pragma unroll
        for(int c=0;c<16;c++) acc[c]*=rr;
        m = newm;
      }
      s += e;
      #pragma unroll
      for(int c=0;c<16;c++) acc[c] += e*v_s[mm][c];
    }
  }
  red[sub][qi][0]=m; red[sub][qi][1]=s;
  #pragma unroll
  for(int c=0;c<16;c++) red[sub][qi][2+c]=acc[c];
  __syncthreads();
  if(sub==0){
    int n = qn_s[qi];
    if(n>=0){
      float M=-1e30f;
      #pragma unroll
      for(int j=0;j<4;j++) M=fmaxf(M,red[j][qi][0]);
      float S=0.f; float o[16];
      #pragma unroll
      for(int c=0;c<16;c++) o[c]=0.f;
      #pragma unroll
      for(int j=0;j<4;j++){ float e=__expf(red[j][qi][0]-M); S += e*red[j][qi][1];
        #pragma unroll
        for(int c=0;c<16;c++) o[c] += e*red[j][qi][2+c]; }
      float inv = 1.f/S;
      #pragma unroll
      for(int c=0;c<16;c++) att[((size_t)b*NQ+n)*128 + h*16 + c] = o[c]*inv;
    }
  }
}

// ---------------- fused: proj+LN1 -> qc (LDS) -> offset matvec + attn-weight softmax ----------------
__global__ void __launch_bounds__(384) k_q2(
    const float* __restrict__ att, const float* __restrict__ sa_wo, const float* __restrict__ sa_bo,
    float* __restrict__ x, const float* __restrict__ ln1_g, const float* __restrict__ ln1_b,
    const float* __restrict__ qpe,
    const float* __restrict__ dow, const float* __restrict__ dob,
    const float* __restrict__ daw, const float* __restrict__ dab,
    float* __restrict__ offb, float* __restrict__ awb){
  int r0 = blockIdx.x*8; int t = threadIdx.x; // 384 threads
  __shared__ float s_att[8][128];
  __shared__ float s_qc[8][128];
  __shared__ float s_m[8][2][2];
  __shared__ float s_aw[8][130];
  for(int i=t;i<1024;i+=384){ int r=i>>7, c=i&127; s_att[r][c]=att[(size_t)(r0+r)*128+c]; }
  __syncthreads();
  int lane = t&63, wid = (t>>6)&1;
  float v[8];
  if(t < 128){
    int d = t;
    float acc[8];
    #pragma unroll
    for(int r=0;r<8;r++) acc[r]=sa_bo[d];
    #pragma unroll 4
    for(int c=0;c<128;c++){ float wv = sa_wo[c*128+d];
      #pragma unroll
      for(int r=0;r<8;r++) acc[r] += s_att[r][c]*wv; }
    #pragma unroll
    for(int r=0;r<8;r++){
      v[r] = acc[r] + x[(size_t)(r0+r)*128 + d];
      float s1=v[r], s2=v[r]*v[r];
      for(int o=32;o>0;o>>=1){ s1 += __shfl_down(s1,o); s2 += __shfl_down(s2,o); }
      if(lane==0){ s_m[r][wid][0]=s1; s_m[r][wid][1]=s2; }
    }
  }
  __syncthreads();
  if(t < 128){
    int d = t;
    #pragma unroll
    for(int r=0;r<8;r++){
      float S1=s_m[r][0][0]+s_m[r][1][0], S2=s_m[r][0][1]+s_m[r][1][1];
      float mean=S1*(1.f/128.f), var=S2*(1.f/128.f)-mean*mean;
      float rs=rsqrtf(var+1e-5f);
      float o=(v[r]-mean)*rs*ln1_g[d]+ln1_b[d];
      x[(size_t)(r0+r)*128+d]=o;
      s_qc[r][d]=o+qpe[(size_t)(r0+r)*128+d];
    }
  }
  __syncthreads();
  if(t < 256){
    int d = t;
    float acc[8];
    #pragma unroll
    for(int r=0;r<8;r++) acc[r]=dob[d];
    #pragma unroll 4
    for(int c=0;c<128;c++){ float wv = dow[(size_t)c*256+d];
      #pragma unroll
      for(int r=0;r<8;r++) acc[r] += s_qc[r][c]*wv; }
    #pragma unroll
    for(int r=0;r<8;r++) offb[(size_t)(r0+r)*256+d]=acc[r];
  } else {
    int d = t - 256;
    float acc[8];
    #pragma unroll
    for(int r=0;r<8;r++) acc[r]=dab[d];
    #pragma unroll 4
    for(int c=0;c<128;c++){ float wv = daw[(size_t)c*128+d];
      #pragma unroll
      for(int r=0;r<8;r++) acc[r] += s_qc[r][c]*wv; }
    #pragma unroll
    for(int r=0;r<8;r++) s_aw[r][d]=acc[r];
  }
  __syncthreads();
  if(t < 64){
    int r = t>>3, h = t&7;
    float mx=-1e30f;
    #pragma unroll
    for(int i=0;i<16;i++) mx = fmaxf(mx, s_aw[r][h*16+i]);
    float e[16]; float sm=0.f;
    #pragma unroll
    for(int i=0;i<16;i++){ e[i]=__expf(s_aw[r][h*16+i]-mx); sm+=e[i]; }
    float inv = 1.f/sm;
    #pragma unroll
    for(int i=0;i<16;i++) awb[(size_t)(r0+r)*128 + h*16+i] = e[i]*inv;
  }
}

// ---------------- deformable bilinear sampling ----------------
__global__ void k_sample(const float* __restrict__ qpos, const int* __restrict__ view,
                         const float* __restrict__ offb, const float* __restrict__ awb,
                         const unsigned short* __restrict__ value, float* __restrict__ ca){
  int n = blockIdx.x, b = blockIdx.y;
  size_t row = (size_t)b*NQ + n;
  int t = threadIdx.x;
  int h = t>>4, lp = t&15, lvl = lp>>2;
  float rx = sigm(qpos[row*2]), ry = sigm(qpos[row*2+1]);
  int vw = view[row];
  int w = c_W[lvl], hh = c_H[lvl];
  float ox = offb[row*256 + t*2], oy = offb[row*256 + t*2+1];
  float a = awb[row*128 + t];
  float lx = rx*(float)w + ox - 0.5f;
  float ly = ry*(float)hh + oy - 0.5f;
  float x0f = floorf(lx), y0f = floorf(ly);
  float fx = lx - x0f, fy = ly - y0f;
  int x0 = (int)x0f, y0 = (int)y0f;
  float samp[16];
  #pragma unroll
  for(int c=0;c<16;c++) samp[c]=0.f;
  size_t brow = ((size_t)(b*VV + vw))*LTOT + c_S[lvl];
  #pragma unroll
  for(int dy=0;dy<2;dy++){
    #pragma unroll
    for(int dx=0;dx<2;dx++){
      int xi=x0+dx, yi=y0+dy;
      if(xi<0||xi>=w||yi<0||yi>=hh) continue;
      float wt = (dx?fx:(1.f-fx))*(dy?fy:(1.f-fy));
      const uint4* vp = reinterpret_cast<const uint4*>(value + (brow + (size_t)yi*w + xi)*CC + h*16);
      uint4 u0 = vp[0], u1 = vp[1];
      samp[0] += wt*bflo(u0.x); samp[1] += wt*bfhi(u0.x);
      samp[2] += wt*bflo(u0.y); samp[3] += wt*bfhi(u0.y);
      samp[4] += wt*bflo(u0.z); samp[5] += wt*bfhi(u0.z);
      samp[6] += wt*bflo(u0.w); samp[7] += wt*bfhi(u0.w);
      samp[8] += wt*bflo(u1.x); samp[9] += wt*bfhi(u1.x);
      samp[10]+= wt*bflo(u1.y); samp[11]+= wt*bfhi(u1.y);
      samp[12]+= wt*bflo(u1.z); samp[13]+= wt*bfhi(u1.z);
      samp[14]+= wt*bflo(u1.w); samp[15]+= wt*bfhi(u1.w);
    }
  }
  __shared__ float sred[128][17];
  #pragma unroll
  for(int c=0;c<16;c++) sred[t][c] = a*samp[c];
  __syncthreads();
  int h2=t>>4, c2=t&15;
  float sum=0.f;
  #pragma unroll
  for(int j=0;j<16;j++) sum += sred[h2*16+j][c2];
  ca[row*128 + t] = sum;
}

// ---------------- fused tail: proj_ln2 + FFN1 + FFN2/LN3 + head ----------------
__global__ void __launch_bounds__(128) k_tail(
    const float* __restrict__ ca, const float* __restrict__ dOw, const float* __restrict__ dOb,
    const float* __restrict__ xres,
    const float* __restrict__ ln2_g, const float* __restrict__ ln2_b,
    const float* __restrict__ fw1, const float* __restrict__ fb1,
    const float* __restrict__ fw2, const float* __restrict__ fb2,
    const float* __restrict__ ln3_g, const float* __restrict__ ln3_b,
    const float* __restrict__ pw1, const float* __restrict__ pb1,
    const float* __restrict__ pw2, const float* __restrict__ pb2,
    const int* __restrict__ counts, const int* __restrict__ view,
    const float* __restrict__ pos, float* __restrict__ dout){
  int r0 = blockIdx.x*4; int d = threadIdx.x;  // 128 threads
  __shared__ float s_a[4][256];
  __shared__ float s_x[4][128];
  __shared__ float s_m[4][2][2];
  __shared__ float s_res[4][6];
  int lane = d&63, wid = d>>6;

  #pragma unroll
  for(int r=0;r<4;r++) s_a[r][d] = ca[(size_t)(r0+r)*128 + d];
  __syncthreads();

  float acc[4];
  #pragma unroll
  for(int r=0;r<4;r++) acc[r]=dOb[d];
  #pragma unroll 4
  for(int c=0;c<128;c++){ float wv = dOw[c*128+d];
    #pragma unroll
    for(int r=0;r<4;r++) acc[r] += s_a[r][c]*wv; }
  float v[4];
  #pragma unroll
  for(int r=0;r<4;r++){
    v[r] = acc[r] + xres[(size_t)(r0+r)*128 + d];
    float s1=v[r], s2=v[r]*v[r];
    for(int o=32;o>0;o>>=1){ s1 += __shfl_down(s1,o); s2 += __shfl_down(s2,o); }
    if(lane==0){ s_m[r][wid][0]=s1; s_m[r][wid][1]=s2; }
  }
  __syncthreads();
  #pragma unroll
  for(int r=0;r<4;r++){
    float S1=s_m[r][0][0]+s_m[r][1][0], S2=s_m[r][0][1]+s_m[r][1][1];
    float mean=S1*(1.f/128.f), var=S2*(1.f/128.f)-mean*mean;
    float rs=rsqrtf(var+1e-5f);
    s_x[r][d]=(v[r]-mean)*rs*ln2_g[d]+ln2_b[d];
  }
  __syncthreads();

  float a2a[4], a2b[4];
  #pragma unroll
  for(int r=0;r<4;r++){ a2a[r]=fb1[d]; a2b[r]=fb1[d+128]; }
  #pragma unroll 4
  for(int c=0;c<128;c++){ float w0 = fw1[c*256+d], w1_ = fw1[c*256+d+128];
    #pragma unroll
    for(int r=0;r<4;r++){ float xv = s_x[r][c]; a2a[r] += xv*w0; a2b[r] += xv*w1_; } }
  __syncthreads();
  #pragma unroll
  for(int r=0;r<4;r++){ s_a[r][d]=fmaxf(a2a[r],0.f); s_a[r][d+128]=fmaxf(a2b[r],0.f); }
  __syncthreads();

  float a3[4];
  #pragma unroll
  for(int r=0;r<4;r++) a3[r]=fb2[d];
  #pragma unroll 4
  for(int c=0;c<256;c++){ float wv = fw2[c*128+d];
    #pragma unroll
    for(int r=0;r<4;r++) a3[r] += s_a[r][c]*wv; }
  #pragma unroll
  for(int r=0;r<4;r++){
    v[r] = a3[r] + s_x[r][d];
    float s1=v[r], s2=v[r]*v[r];
    for(int o=32;o>0;o>>=1){ s1 += __shfl_down(s1,o); s2 += __shfl_down(s2,o); }
    if(lane==0){ s_m[r][wid][0]=s1; s_m[r][wid][1]=s2; }
  }
  __syncthreads();
  #pragma unroll
  for(int r=0;r<4;r++){
    float S1=s_m[r][0][0]+s_m[r][1][0], S2=s_m[r][0][1]+s_m[r][1][1];
    float mean=S1*(1.f/128.f), var=S2*(1.f/128.f)-mean*mean;
    float rs=rsqrtf(var+1e-5f);
    float o=(v[r]-mean)*rs*ln3_g[d]+ln3_b[d];
    int row=r0+r; int b=row/NQ, n=row%NQ;
    bool val = counts[b*VV + view[row]] > 1;
    float oz = val ? o : 0.f;
    s_x[r][d]=oz;
    dout[((size_t)b*CC + d)*NQ + n]=oz;
  }
  __syncthreads();

  float a4[4];
  #pragma unroll
  for(int r=0;r<4;r++) a4[r]=pb1[d];
  #pragma unroll 4
  for(int c=0;c<128;c++){ float wv = pw1[c*128+d];
    #pragma unroll
    for(int r=0;r<4;r++) a4[r] += s_x[r][c]*wv; }
  #pragma unroll
  for(int r=0;r<4;r++) s_a[r][d]=fmaxf(a4[r],0.f);
  __syncthreads();

  if(d < 24){
    int r = d/6, o = d%6;
    float a5 = pb2[o];
    #pragma unroll 4
    for(int c=0;c<128;c++) a5 += s_a[r][c]*pw2[c*6+o];
    s_res[r][o] = a5;
  }
  __syncthreads();
  if(d < 4){
    int r = d; int row = r0+r; int b=row/NQ, n=row%NQ;
    const int O1 = BB*CC*NQ;
    const int O2 = O1 + BB*NQ*2;
    const int O3 = O2 + BB*2*NQ;
    const int O4 = O3 + BB*4*NQ;
    float p0=pos[row*2], p1=pos[row*2+1];
    float cr0 = s_res[r][0]+p0, cr1 = s_res[r][1]+p1;
    dout[O1 + row*2]   = cr0;
    dout[O1 + row*2+1] = cr1;
    float cen0 = sigm(cr0), cen1 = sigm(cr1);
    dout[O2 + (b*2+0)*NQ + n] = cen0;
    dout[O2 + (b*2+1)*NQ + n] = cen1;
    float f0=sigm(s_res[r][2]), f1=sigm(s_res[r][3]), f2=sigm(s_res[r][4]), f3=sigm(s_res[r][5]);
    dout[O3 + (b*4+0)*NQ + n] = f0;
    dout[O3 + (b*4+1)*NQ + n] = f1;
    dout[O3 + (b*4+2)*NQ + n] = f2;
    dout[O3 + (b*4+3)*NQ + n] = f3;
    float bw=f0+f2, bh=f1+f3;
    float cx=(2.f*cen0 - f0 + f2)*0.5f;
    float cy=(2.f*cen1 - f1 + f3)*0.5f;
    dout[O4 + (b*4+0)*NQ + n] = cx;
    dout[O4 + (b*4+1)*NQ + n] = cy;
    dout[O4 + (b*4+2)*NQ + n] = bw;
    dout[O4 + (b*4+3)*NQ + n] = bh;
  }
}

extern "C" void kernel_launch(void* const* d_in, const int* in_sizes, int n_in,
                              void* d_out, int out_size, void* d_ws, size_t ws_size,
                              hipStream_t stream){
  (void)in_sizes; (void)n_in; (void)out_size; (void)ws_size;
  const float* in_iqf  = (const float*)d_in[0];
  const float* in_qpos = (const float*)d_in[1];
  const float* in_feat[4] = {(const float*)d_in[2],(const float*)d_in[3],(const float*)d_in[4],(const float*)d_in[5]};
  const float* in_kpos = (const float*)d_in[6];
  const float* sp_w1=(const float*)d_in[7], *sp_b1=(const float*)d_in[8], *sp_w2=(const float*)d_in[9], *sp_b2=(const float*)d_in[10];
  const float* cp_w1=(const float*)d_in[11], *cp_b1=(const float*)d_in[12], *cp_w2=(const float*)d_in[13], *cp_b2=(const float*)d_in[14];
  const float* sa_wqkv=(const float*)d_in[15], *sa_bqkv=(const float*)d_in[16], *sa_wo=(const float*)d_in[17], *sa_bo=(const float*)d_in[18];
  const float* ln1_g=(const float*)d_in[19], *ln1_b=(const float*)d_in[20];
  const float* dvw=(const float*)d_in[21], *dvb=(const float*)d_in[22];
  const float* dow=(const float*)d_in[23], *dob=(const float*)d_in[24];
  const float* daw=(const float*)d_in[25], *dab=(const float*)d_in[26];
  const float* dOw=(const float*)d_in[27], *dOb=(const float*)d_in[28];
  const float* ln2_g=(const float*)d_in[29], *ln2_b=(const float*)d_in[30];
  const float* fw1=(const float*)d_in[31], *fb1=(const float*)d_in[32], *fw2=(const float*)d_in[33], *fb2=(const float*)d_in[34];
  const float* ln3_g=(const float*)d_in[35], *ln3_b=(const float*)d_in[36];
  const float* pw1=(const float*)d_in[37], *pb1=(const float*)d_in[38], *pw2=(const float*)d_in[39], *pb2=(const float*)d_in[40];
  const int* in_view = (const int*)d_in[41];
  float* out = (float*)d_out;

  char* ws = (char*)d_ws;
  unsigned short* value = (unsigned short*)ws;                       // 91,392,000 B
  unsigned short* kvpe  = (unsigned short*)(ws + 91392000);          //  7,616,000 B
  float* f = (float*)(ws + 91392000 + 7616000);
  float* qpe  = f;               // 307200
  float* x    = f + 307200;      // 307200
  float* qkv  = f + 614400;      // 921600
  float* att  = f + 1536000;     // 307200
  float* offb = f + 2150400;     // 614400
  float* awb  = f + 2764800;     // 307200
  float* ca   = f + 3072000;     // 307200
  int* counts = (int*)(f + 4300800);   // 12 ints
  int* order  = (int*)(f + 4300816);   // B*VV*NQ = 14400 ints
  unsigned short* wtb   = (unsigned short*)(f + 4315216);  // 32768 B
  unsigned short* cw2tb = (unsigned short*)(f + 4323408);  // 32768 B

  k_misc<<<dim3(BB+32+76+600),dim3(256),0,stream>>>(in_view,order,counts,dvw,wtb,
      cp_w2,cw2tb,in_iqf,x,in_qpos,sp_w1,sp_b1,sp_w2,sp_b2,qpe);
  k_kvpe2<<<dim3((LTOT+63)/64),dim3(256),0,stream>>>(in_kpos,cp_w1,cp_b1,cw2tb,cp_b2,wtb,dvb,kvpe);
  k_value_qkv<<<dim3(QKVB + 466*12),dim3(256),0,stream>>>(in_feat[0],in_feat[1],in_feat[2],in_feat[3],
      kvpe,wtb,value,x,qpe,sa_wqkv,sa_bqkv,qkv);
  k_attn_v<<<dim3((NQ+QT2-1)/QT2, VV*HH, BB),dim3(256),0,stream>>>(qkv,order,counts,att);
  k_q2<<<dim3(NROWS/8),dim3(384),0,stream>>>(att,sa_wo,sa_bo,x,ln1_g,ln1_b,qpe,
      dow,dob,daw,dab,offb,awb);
  k_sample<<<dim3(NQ,BB),dim3(128),0,stream>>>(in_qpos,in_view,offb,awb,value,ca);
  k_tail<<<dim3(NROWS/4),dim3(128),0,stream>>>(ca,dOw,dOb,x,ln2_g,ln2_b,
      fw1,fb1,fw2,fb2,ln3_g,ln3_b,pw1,pb1,pw2,pb2,counts,in_view,in_qpos,out);
}